// Round 1
// baseline (65.729 us; speedup 1.0000x reference)
//
#include <hip/hip_runtime.h>
#include <math.h>

// CosineSSMLoss: loss = sum_b || Zp_b^T Zp_b - Zs_b^T Zs_b ||_F^2 / (B*N*N)
// with columns of Zp/Zs L2-normalized over C. Since C=4, use the identity
//   sum_{n,m} (u_n.u_m)^2          = ||U U^T||_F^2   (4x4)
//   sum_{n,m} (u_n.u_m)(v_n.v_m)   = ||U V^T||_F^2   (4x4)
// => loss = sum_b (||Gu||^2 + ||Gv||^2 - 2||M||^2) / (B*N^2)
// One pass over the 512 KB of input instead of 2x 67M-entry Gram matrices.

#define NORM_EPS 1e-12f

__global__ __launch_bounds__(1024) void cosine_ssm_kernel(
    const float* __restrict__ x_pred,
    const float* __restrict__ x_src,
    float* __restrict__ out)
{
    constexpr int C = 4, N = 4096;        // N = H*W = 64*64
    const int b    = blockIdx.x;          // one block per batch
    const int tid  = threadIdx.x;         // 0..1023
    const int lane = tid & 63;
    const int wave = tid >> 6;            // 0..15

    const float* pb = x_pred + (size_t)b * C * N;
    const float* sb = x_src  + (size_t)b * C * N;

    // Per-thread partial 4x4 Gram accumulators (Gu, Gv symmetric -> 10 each; M full 16)
    float gu[10], gv[10], m[16];
#pragma unroll
    for (int i = 0; i < 10; ++i) { gu[i] = 0.f; gv[i] = 0.f; }
#pragma unroll
    for (int i = 0; i < 16; ++i) m[i] = 0.f;

    // 1024 threads * 4 consecutive n each = 4096 positions, exactly one float4 per channel
    const int n0 = tid * 4;

    float pv[4][4], sv[4][4];   // [channel][k within float4]
#pragma unroll
    for (int c = 0; c < C; ++c) {
        float4 t = *(const float4*)(pb + c * N + n0);
        pv[c][0] = t.x; pv[c][1] = t.y; pv[c][2] = t.z; pv[c][3] = t.w;
        float4 q = *(const float4*)(sb + c * N + n0);
        sv[c][0] = q.x; sv[c][1] = q.y; sv[c][2] = q.z; sv[c][3] = q.w;
    }

#pragma unroll
    for (int k = 0; k < 4; ++k) {
        float np = 0.f, ns = 0.f;
#pragma unroll
        for (int c = 0; c < 4; ++c) {
            np += pv[c][k] * pv[c][k];
            ns += sv[c][k] * sv[c][k];
        }
        const float ip = 1.f / fmaxf(sqrtf(np), NORM_EPS);   // matches F.normalize eps
        const float is = 1.f / fmaxf(sqrtf(ns), NORM_EPS);
        float u[4], v[4];
#pragma unroll
        for (int c = 0; c < 4; ++c) { u[c] = pv[c][k] * ip; v[c] = sv[c][k] * is; }

        int idx = 0;
#pragma unroll
        for (int i = 0; i < 4; ++i)
#pragma unroll
            for (int j = i; j < 4; ++j) {
                gu[idx] += u[i] * u[j];
                gv[idx] += v[i] * v[j];
                ++idx;
            }
#pragma unroll
        for (int i = 0; i < 4; ++i)
#pragma unroll
            for (int j = 0; j < 4; ++j)
                m[i * 4 + j] += u[i] * v[j];
    }

    // Pack 36 partials and reduce across the block (wave shuffle, then LDS across 16 waves)
    float acc[36];
#pragma unroll
    for (int i = 0; i < 10; ++i) { acc[i] = gu[i]; acc[10 + i] = gv[i]; }
#pragma unroll
    for (int i = 0; i < 16; ++i) acc[20 + i] = m[i];

#pragma unroll
    for (int off = 32; off >= 1; off >>= 1) {
#pragma unroll
        for (int i = 0; i < 36; ++i)
            acc[i] += __shfl_down(acc[i], off, 64);
    }

    __shared__ float lds[16][36];
    if (lane == 0) {
#pragma unroll
        for (int i = 0; i < 36; ++i) lds[wave][i] = acc[i];
    }
    __syncthreads();

    if (tid < 36) {
        float s = 0.f;
#pragma unroll
        for (int w = 0; w < 16; ++w) s += lds[w][tid];
        lds[0][tid] = s;
    }
    __syncthreads();

    if (tid == 0) {
        const float* g = &lds[0][0];
        // symmetric storage order: (0,0)(0,1)(0,2)(0,3)(1,1)(1,2)(1,3)(2,2)(2,3)(3,3)
        // diagonals at 0,4,7,9; off-diagonals counted twice in the Frobenius norm
        const float fu = g[0]*g[0] + g[4]*g[4] + g[7]*g[7] + g[9]*g[9]
                       + 2.f*(g[1]*g[1] + g[2]*g[2] + g[3]*g[3] + g[5]*g[5] + g[6]*g[6] + g[8]*g[8]);
        const float* h = &lds[0][10];
        const float fv = h[0]*h[0] + h[4]*h[4] + h[7]*h[7] + h[9]*h[9]
                       + 2.f*(h[1]*h[1] + h[2]*h[2] + h[3]*h[3] + h[5]*h[5] + h[6]*h[6] + h[8]*h[8]);
        const float* mm = &lds[0][20];
        float fm = 0.f;
#pragma unroll
        for (int i = 0; i < 16; ++i) fm += mm[i] * mm[i];

        // loss contribution of this batch: (fu + fv - 2*fm) / (B*N*N)
        const float contrib = (fu + fv - 2.f * fm) * (1.0f / (4.0f * 4096.0f * 4096.0f));
        atomicAdd(out, contrib);
    }
}

extern "C" void kernel_launch(void* const* d_in, const int* in_sizes, int n_in,
                              void* d_out, int out_size, void* d_ws, size_t ws_size,
                              hipStream_t stream) {
    const float* x_pred = (const float*)d_in[0];
    const float* x_src  = (const float*)d_in[1];
    float* out = (float*)d_out;

    // d_out is poisoned (0xAA) before every timed replay — zero it on-stream
    // (async memset is graph-capture safe), then 4 blocks atomicAdd into it.
    hipMemsetAsync(out, 0, sizeof(float), stream);
    cosine_ssm_kernel<<<4, 1024, 0, stream>>>(x_pred, x_src, out);
}

// Round 2
// 59.540 us; speedup vs baseline: 1.1040x; 1.1040x over previous
//
#include <hip/hip_runtime.h>
#include <math.h>

// CosineSSMLoss: loss = sum_b || Zp_b^T Zp_b - Zs_b^T Zs_b ||_F^2 / (B*N*N)
// with columns L2-normalized over C. C=4, so collapse via
//   ||A_p - A_s||_F^2 = ||Gu||_F^2 + ||Gv||_F^2 - 2||M||_F^2
// where Gu = U U^T, Gv = V V^T, M = U V^T are 4x4 (U,V = normalized C x N).
// Kernel 1: 64 blocks (4 batches x 16 slices) x 64 threads, one float4 per
//           channel per thread; block-reduce 36 partials; plain-store to ws.
// Kernel 2: 1 block reduces 64 slots -> per-batch 4x4 Grams -> scalar loss.
// No memset, no atomics: ws layout ws[i*64 + (b*16+s)], i in [0,36).

#define NORM_EPS 1e-12f

__global__ __launch_bounds__(64) void cosine_ssm_partial(
    const float* __restrict__ x_pred,
    const float* __restrict__ x_src,
    float* __restrict__ ws)
{
    constexpr int C = 4, N = 4096;     // N = H*W
    const int slot = blockIdx.x;       // 0..63
    const int b    = slot >> 4;        // batch
    const int s    = slot & 15;        // slice within batch
    const int lane = threadIdx.x;      // 0..63 (one wave)

    const float* pb = x_pred + (size_t)b * C * N;
    const float* sb = x_src  + (size_t)b * C * N;
    const int n0 = s * 256 + lane * 4; // 16 slices * 64 lanes * 4 = 4096

    float pv[4][4], sv[4][4];          // [channel][k]
#pragma unroll
    for (int c = 0; c < C; ++c) {
        float4 t = *(const float4*)(pb + c * N + n0);
        pv[c][0] = t.x; pv[c][1] = t.y; pv[c][2] = t.z; pv[c][3] = t.w;
        float4 q = *(const float4*)(sb + c * N + n0);
        sv[c][0] = q.x; sv[c][1] = q.y; sv[c][2] = q.z; sv[c][3] = q.w;
    }

    float acc[36];                     // [0..9]=Gu sym, [10..19]=Gv sym, [20..35]=M
#pragma unroll
    for (int i = 0; i < 36; ++i) acc[i] = 0.f;

#pragma unroll
    for (int k = 0; k < 4; ++k) {
        float np = 0.f, ns = 0.f;
#pragma unroll
        for (int c = 0; c < 4; ++c) {
            np += pv[c][k] * pv[c][k];
            ns += sv[c][k] * sv[c][k];
        }
        const float ip = 1.f / fmaxf(sqrtf(np), NORM_EPS);  // F.normalize eps
        const float is = 1.f / fmaxf(sqrtf(ns), NORM_EPS);
        float u[4], v[4];
#pragma unroll
        for (int c = 0; c < 4; ++c) { u[c] = pv[c][k] * ip; v[c] = sv[c][k] * is; }

        int idx = 0;
#pragma unroll
        for (int i = 0; i < 4; ++i)
#pragma unroll
            for (int j = i; j < 4; ++j) {
                acc[idx]      += u[i] * u[j];
                acc[10 + idx] += v[i] * v[j];
                ++idx;
            }
#pragma unroll
        for (int i = 0; i < 4; ++i)
#pragma unroll
            for (int j = 0; j < 4; ++j)
                acc[20 + i * 4 + j] += u[i] * v[j];
    }

    // wave-wide butterfly-free reduce to lane 0
#pragma unroll
    for (int off = 32; off >= 1; off >>= 1) {
#pragma unroll
        for (int i = 0; i < 36; ++i)
            acc[i] += __shfl_down(acc[i], off, 64);
    }

    if (lane == 0) {
#pragma unroll
        for (int i = 0; i < 36; ++i)
            ws[i * 64 + slot] = acc[i];    // [i][slot] so finalize reads runs of 16
    }
}

__global__ __launch_bounds__(192) void cosine_ssm_finalize(
    const float* __restrict__ ws,
    float* __restrict__ out)
{
    __shared__ float g[4][36];
    __shared__ float contrib[4];
    const int t = threadIdx.x;         // 0..191; 144 active for the gather

    if (t < 144) {
        const int b = t / 36;
        const int i = t - b * 36;
        const float* src = ws + i * 64 + b * 16;  // 16 contiguous slice-partials
        float ssum = 0.f;
#pragma unroll
        for (int s = 0; s < 16; ++s) ssum += src[s];
        g[b][i] = ssum;
    }
    __syncthreads();

    if (t < 4) {
        const float* a = g[t];
        // symmetric order: (0,0)(0,1)(0,2)(0,3)(1,1)(1,2)(1,3)(2,2)(2,3)(3,3)
        // diagonals at 0,4,7,9; off-diagonals doubled in the Frobenius norm
        const float fu = a[0]*a[0] + a[4]*a[4] + a[7]*a[7] + a[9]*a[9]
                       + 2.f*(a[1]*a[1] + a[2]*a[2] + a[3]*a[3] + a[5]*a[5] + a[6]*a[6] + a[8]*a[8]);
        const float* h = a + 10;
        const float fv = h[0]*h[0] + h[4]*h[4] + h[7]*h[7] + h[9]*h[9]
                       + 2.f*(h[1]*h[1] + h[2]*h[2] + h[3]*h[3] + h[5]*h[5] + h[6]*h[6] + h[8]*h[8]);
        const float* mm = a + 20;
        float fm = 0.f;
#pragma unroll
        for (int i = 0; i < 16; ++i) fm += mm[i] * mm[i];
        contrib[t] = fu + fv - 2.f * fm;
    }
    __syncthreads();

    if (t == 0) {
        const float scale = 1.0f / (4.0f * 4096.0f * 4096.0f);  // 1/(B*N*N)
        out[0] = (contrib[0] + contrib[1] + contrib[2] + contrib[3]) * scale;
    }
}

extern "C" void kernel_launch(void* const* d_in, const int* in_sizes, int n_in,
                              void* d_out, int out_size, void* d_ws, size_t ws_size,
                              hipStream_t stream) {
    const float* x_pred = (const float*)d_in[0];
    const float* x_src  = (const float*)d_in[1];
    float* ws  = (float*)d_ws;    // 36*64 floats = 9216 B of scratch
    float* out = (float*)d_out;

    cosine_ssm_partial<<<64, 64, 0, stream>>>(x_pred, x_src, ws);
    cosine_ssm_finalize<<<1, 192, 0, stream>>>(ws, out);
}